// Round 3
// 629.246 us; speedup vs baseline: 1.0365x; 1.0365x over previous
//
#include <hip/hip_runtime.h>

#define N_BINS 15
#define NCLASS 128

typedef float fx4 __attribute__((ext_vector_type(4)));

__global__ void zero_out_kernel(float* __restrict__ out) {
    int i = threadIdx.x;
    if (i < 2 * N_BINS) out[i] = 0.0f;
}

// DPP quad_perm cross-lane moves (VALU pipe, no LDS/DS latency).
// 0xB1 = [1,0,3,2] (xor 1), 0x4E = [2,3,0,1] (xor 2).
__device__ __forceinline__ int dpp_xor1_i(int x) {
    return __builtin_amdgcn_mov_dpp(x, 0xB1, 0xF, 0xF, true);
}
__device__ __forceinline__ int dpp_xor2_i(int x) {
    return __builtin_amdgcn_mov_dpp(x, 0x4E, 0xF, 0xF, true);
}
__device__ __forceinline__ float dpp_xor1_f(float x) {
    return __int_as_float(dpp_xor1_i(__float_as_int(x)));
}
__device__ __forceinline__ float dpp_xor2_f(float x) {
    return __int_as_float(dpp_xor2_i(__float_as_int(x)));
}

__global__ __launch_bounds__(256, 4) void conf_hist_kernel(
        const float* __restrict__ logits,
        const int* __restrict__ labels,
        float* __restrict__ out,
        int n) {
    __shared__ int hist[2 * N_BINS];
    if (threadIdx.x < 2 * N_BINS) hist[threadIdx.x] = 0;
    __syncthreads();

    const int lane = threadIdx.x & 63;
    const int quad = lane >> 2;  // 16 quads/wave, one sample each
    const int t = lane & 3;      // position within quad
    const int wavesPerBlock = blockDim.x >> 6;
    const int wave = blockIdx.x * wavesPerBlock + (threadIdx.x >> 6);
    const int numWaves = gridDim.x * wavesPerBlock;
    const int stride = numWaves * 16;

    // ---- prologue: load iteration 0 into buffer A ----
    int base = wave * 16;
    fx4 cA[8];
    int labA = 0;
    {
        const int s = base + quad;
        if (base < n && s < n) {
            const float* row = logits + (size_t)s * NCLASS + t * 4;
            #pragma unroll
            for (int j = 0; j < 8; ++j)
                cA[j] = __builtin_nontemporal_load((const fx4*)(row + j * 16));
            labA = labels[s];  // all 4 lanes of quad load same addr (one 64B seg/wave)
        }
    }

    for (; base < n; base += stride) {
        const int s = base + quad;  // quad-uniform predicate

        // ---- software pipeline: issue NEXT iteration's loads first ----
        const int nbase = base + stride;
        const int ns = nbase + quad;
        fx4 cB[8];
        int labB = 0;
        if (nbase < n && ns < n) {
            const float* row = logits + (size_t)ns * NCLASS + t * 4;
            #pragma unroll
            for (int j = 0; j < 8; ++j)
                cB[j] = __builtin_nontemporal_load((const fx4*)(row + j * 16));
            labB = labels[ns];
        } else {
            #pragma unroll
            for (int j = 0; j < 8; ++j) cB[j] = (fx4)(0.0f);
        }

        // ---- compute on buffer A (loads for B in flight behind this) ----
        if (s < n) {
            // per-chunk argmax; strict > keeps first (lowest) index
            float m[8]; int mi[8];
            #pragma unroll
            for (int j = 0; j < 8; ++j) {
                float mm = cA[j][0]; int ii = 0;
                if (cA[j][1] > mm) { mm = cA[j][1]; ii = 1; }
                if (cA[j][2] > mm) { mm = cA[j][2]; ii = 2; }
                if (cA[j][3] > mm) { mm = cA[j][3]; ii = 3; }
                m[j] = mm; mi[j] = j * 16 + t * 4 + ii;
            }
            // tree 8->1; left operand always has lower indices, > keeps left on tie
            #pragma unroll
            for (int stp = 1; stp < 8; stp <<= 1) {
                #pragma unroll
                for (int j = 0; j < 8; j += 2 * stp) {
                    if (m[j + stp] > m[j]) { m[j] = m[j + stp]; mi[j] = mi[j + stp]; }
                }
            }
            float bm = m[0]; int bi = mi[0];

            // quad butterfly via DPP (tie-break by index explicitly)
            {
                float om = dpp_xor1_f(bm); int oi = dpp_xor1_i(bi);
                if (om > bm || (om == bm && oi < bi)) { bm = om; bi = oi; }
            }
            {
                float om = dpp_xor2_f(bm); int oi = dpp_xor2_i(bi);
                if (om > bm || (om == bm && oi < bi)) { bm = om; bi = oi; }
            }

            // sum exp(l - max), pairwise tree
            float s4[8];
            #pragma unroll
            for (int j = 0; j < 8; ++j)
                s4[j] = (__expf(cA[j][0] - bm) + __expf(cA[j][1] - bm))
                      + (__expf(cA[j][2] - bm) + __expf(cA[j][3] - bm));
            float e = ((s4[0] + s4[1]) + (s4[2] + s4[3]))
                    + ((s4[4] + s4[5]) + (s4[6] + s4[7]));
            e += dpp_xor1_f(e);
            e += dpp_xor2_f(e);

            if (t == 0) {
                float conf = 1.0f / e;
                int bin = (int)(conf * (float)N_BINS);
                bin = bin > (N_BINS - 1) ? (N_BINS - 1) : (bin < 0 ? 0 : bin);
                int col = (bi == labA) ? 0 : 1;  // col 0: correct
                atomicAdd(&hist[bin * 2 + col], 1);
            }
        }

        // ---- rotate buffers (compiler places s_waitcnt for cB here, after compute) ----
        #pragma unroll
        for (int j = 0; j < 8; ++j) cA[j] = cB[j];
        labA = labB;
    }

    __syncthreads();
    if (threadIdx.x < 2 * N_BINS) {
        int c = hist[threadIdx.x];
        if (c != 0) atomicAdd(&out[threadIdx.x], (float)c);
    }
}

extern "C" void kernel_launch(void* const* d_in, const int* in_sizes, int n_in,
                              void* d_out, int out_size, void* d_ws, size_t ws_size,
                              hipStream_t stream) {
    const float* logits = (const float*)d_in[0];
    const int*   labels = (const int*)d_in[1];
    float* out = (float*)d_out;
    const int n = in_sizes[1];  // number of samples

    zero_out_kernel<<<1, 64, 0, stream>>>(out);

    const int block = 256;
    const int grid = 2048;  // 8192 waves, 4 waves/block
    conf_hist_kernel<<<grid, block, 0, stream>>>(logits, labels, out, n);
}